// Round 1
// baseline (302.063 us; speedup 1.0000x reference)
//
#include <hip/hip_runtime.h>
#include <stdint.h>

typedef float f32x4 __attribute__((ext_vector_type(4)));
typedef short bf16x8 __attribute__((ext_vector_type(8)));
typedef unsigned short u16;
typedef unsigned int u32;

#define LDK 72  // padded LDS row stride (elements): 144B rows -> 16B-aligned, reads 2-way-conflict-free

static __device__ __forceinline__ u16 f2bf(float f) {
  union { float f; u32 u; } x; x.f = f;
  return (u16)((x.u + 0x7FFFu + ((x.u >> 16) & 1u)) >> 16);  // RNE
}

static __device__ __forceinline__ bf16x8 ld8(const u16* p0, const u16* p1) {
  bf16x8 v;
  uint2* pv = (uint2*)&v;
  pv[0] = *(const uint2*)p0;
  pv[1] = *(const uint2*)p1;
  return v;
}

static __device__ __forceinline__ f32x4 mma(bf16x8 a, bf16x8 b, f32x4 c) {
  return __builtin_amdgcn_mfma_f32_16x16x32_bf16(a, b, c, 0, 0, 0);
}

// ---------------- f32 -> bf16 convert ----------------
__global__ __launch_bounds__(256) void cvt_bf16(const float* __restrict__ in,
                                                u16* __restrict__ out, int n4) {
  int i = blockIdx.x * blockDim.x + threadIdx.x;
  int stride = gridDim.x * blockDim.x;
  for (; i < n4; i += stride) {
    float4 v = ((const float4*)in)[i];
    ushort4 o;
    o.x = f2bf(v.x); o.y = f2bf(v.y); o.z = f2bf(v.z); o.w = f2bf(v.w);
    ((ushort4*)out)[i] = o;
  }
}

// ---------------- shared 128x128x(K=1024) bf16 GEMM core: C = A * B^T ----------------
// A: [M,1024] row-major bf16, Bmat: [N,1024] row-major bf16 (both K-contiguous)
static __device__ __forceinline__ void gemm128(const u16* __restrict__ A,
                                               const u16* __restrict__ Bmat,
                                               u16* lA, u16* lB,
                                               int bm, int bn, f32x4 (&acc)[4][4]) {
  const int t = threadIdx.x;
  const int lane = t & 63, wave = t >> 6;
  const int wrow = wave >> 1, wcol = wave & 1;   // 2x2 waves of 64x64
  const int g = lane >> 4, r16 = lane & 15;
  for (int kt = 0; kt < 1024; kt += 64) {
    __syncthreads();
    #pragma unroll
    for (int i = 0; i < 4; i++) {               // 1024 chunks of 16B per tile
      int ci = i * 256 + t;
      int r = ci >> 3, c = (ci & 7) * 8;
      *(uint4*)(lA + r * LDK + c) = *(const uint4*)(A + (bm + r) * 1024 + kt + c);
      *(uint4*)(lB + r * LDK + c) = *(const uint4*)(Bmat + (bn + r) * 1024 + kt + c);
    }
    __syncthreads();
    #pragma unroll
    for (int kk = 0; kk < 2; kk++) {
      bf16x8 af[4], bfr[4];
      #pragma unroll
      for (int mi = 0; mi < 4; mi++) {
        const u16* p = lA + (wrow * 64 + mi * 16 + r16) * LDK + kk * 32 + g * 4;
        af[mi] = ld8(p, p + 16);
      }
      #pragma unroll
      for (int nj = 0; nj < 4; nj++) {
        const u16* p = lB + (wcol * 64 + nj * 16 + r16) * LDK + kk * 32 + g * 4;
        bfr[nj] = ld8(p, p + 16);
      }
      #pragma unroll
      for (int mi = 0; mi < 4; mi++)
        #pragma unroll
        for (int nj = 0; nj < 4; nj++)
          acc[mi][nj] = mma(af[mi], bfr[nj], acc[mi][nj]);
    }
  }
}

// ---------------- QKV projection + scatter to per-head Q,K,V^T (bf16) ----------------
__global__ __launch_bounds__(256) void k_gemm_qkv(const u16* __restrict__ xb,
                                                  const u16* __restrict__ wb,
                                                  const float* __restrict__ qkv_b,
                                                  u16* __restrict__ Qs,
                                                  u16* __restrict__ Ks,
                                                  u16* __restrict__ Vt) {
  __shared__ __align__(16) u16 lA[128 * LDK];
  __shared__ __align__(16) u16 lB[128 * LDK];
  f32x4 acc[4][4] = {};
  const int bm = blockIdx.x * 128, bn = blockIdx.y * 128;
  gemm128(xb, wb, lA, lB, bm, bn, acc);
  const int lane = threadIdx.x & 63, wave = threadIdx.x >> 6;
  const int wrow = wave >> 1, wcol = wave & 1;
  const int g = lane >> 4, r16 = lane & 15;
  #pragma unroll
  for (int nj = 0; nj < 4; nj++) {
    int f = bn + wcol * 64 + nj * 16 + r16;      // output feature (0..3071)
    float bias = qkv_b[f];
    int which = f >> 10;                          // 0=q 1=k 2=v
    int fl = f & 1023;
    int h = fl >> 6, dd = fl & 63;
    #pragma unroll
    for (int mi = 0; mi < 4; mi++) {
      int mbase = bm + wrow * 64 + mi * 16 + g * 4;
      #pragma unroll
      for (int rg = 0; rg < 4; rg++) {
        int m = mbase + rg;                       // row = b*2048 + s
        int b = m >> 11, s = m & 2047;
        float val = acc[mi][nj][rg] + bias;
        if (which == 0)
          Qs[(((b * 16 + h) * 2048) + s) * 64 + dd] = f2bf(val * 0.125f);  // fold softmax scale
        else if (which == 1)
          Ks[(((b * 16 + h) * 2048) + s) * 64 + dd] = f2bf(val);
        else
          Vt[(((b * 16 + h) * 64) + dd) * 2048 + s] = f2bf(val);           // transposed for PV B-operand
      }
    }
  }
}

// ---------------- flash attention: per block 128 q rows, 4 waves x 32 q ----------------
__global__ __launch_bounds__(256) void k_attn(const u16* __restrict__ Qs,
                                              const u16* __restrict__ Ks,
                                              const u16* __restrict__ Vt,
                                              u16* __restrict__ ctx) {
  __shared__ __align__(16) u16 lK[64 * LDK];   // [key][dim]
  __shared__ __align__(16) u16 lV[64 * LDK];   // [dv][key]
  const int bh = blockIdx.y, qt = blockIdx.x;
  const int b = bh >> 4, h = bh & 15;
  const u16* Qb = Qs + bh * (2048 * 64);
  const u16* Kb = Ks + bh * (2048 * 64);
  const u16* Vb = Vt + bh * (64 * 2048);
  const int t = threadIdx.x, lane = t & 63, wave = t >> 6;
  const int g = lane >> 4, r16 = lane & 15;
  const int q0 = qt * 128 + wave * 32;

  // Q fragments (B-operand of swapped QK^T): per wave 32 q rows = 2 sub-tiles
  bf16x8 qf[2][2];
  #pragma unroll
  for (int j = 0; j < 2; j++) {
    const u16* qr = Qb + (q0 + j * 16 + r16) * 64;
    qf[j][0] = ld8(qr + g * 4, qr + 16 + g * 4);
    qf[j][1] = ld8(qr + 32 + g * 4, qr + 48 + g * 4);
  }
  float mrun[2] = {-INFINITY, -INFINITY};
  float lrun[2] = {0.f, 0.f};
  f32x4 o[2][4] = {};

  for (int s0 = 0; s0 < 2048; s0 += 64) {
    __syncthreads();
    #pragma unroll
    for (int i = 0; i < 2; i++) {               // stage K tile (64x64) + V^T tile (64x64)
      int ci = i * 256 + t;
      int r = ci >> 3, c = (ci & 7) * 8;
      *(uint4*)(lK + r * LDK + c) = *(const uint4*)(Kb + (s0 + r) * 64 + c);
      *(uint4*)(lV + r * LDK + c) = *(const uint4*)(Vb + r * 2048 + s0 + c);
    }
    __syncthreads();

    // S^T = K * Q^T : D[key][q], q = lane&15, key = 4*(lane>>4)+reg (+16*ks)
    f32x4 st[2][4];
    #pragma unroll
    for (int ks = 0; ks < 4; ks++) {
      const u16* kp = lK + (ks * 16 + r16) * LDK;
      bf16x8 kf0 = ld8(kp + g * 4, kp + 16 + g * 4);
      bf16x8 kf1 = ld8(kp + 32 + g * 4, kp + 48 + g * 4);
      #pragma unroll
      for (int j = 0; j < 2; j++) {
        f32x4 z = {0.f, 0.f, 0.f, 0.f};
        z = mma(kf0, qf[j][0], z);
        z = mma(kf1, qf[j][1], z);
        st[j][ks] = z;
      }
    }

    bf16x8 pa[2][2];
    #pragma unroll
    for (int j = 0; j < 2; j++) {
      float tmax = st[j][0][0];
      #pragma unroll
      for (int ks = 0; ks < 4; ks++)
        #pragma unroll
        for (int rg = 0; rg < 4; rg++) tmax = fmaxf(tmax, st[j][ks][rg]);
      tmax = fmaxf(tmax, __shfl_xor(tmax, 16));
      tmax = fmaxf(tmax, __shfl_xor(tmax, 32));
      float mn = fmaxf(mrun[j], tmax);
      float corr = __expf(mrun[j] - mn);         // exp(-inf)=0 on first tile
      mrun[j] = mn;
      float rs = 0.f;
      #pragma unroll
      for (int ks = 0; ks < 4; ks++)
        #pragma unroll
        for (int rg = 0; rg < 4; rg++) {
          float e = __expf(st[j][ks][rg] - mn);
          rs += e;
          pa[j][ks >> 1][(ks & 1) * 4 + rg] = (short)f2bf(e);  // A-operand of PV, lane-local
        }
      rs += __shfl_xor(rs, 16);
      rs += __shfl_xor(rs, 32);
      lrun[j] = lrun[j] * corr + rs;
      // rescale O (O rows are q = 4g+rg; stats live at lane (q&15))
      float cr[4];
      #pragma unroll
      for (int rg = 0; rg < 4; rg++) cr[rg] = __shfl(corr, g * 4 + rg);
      #pragma unroll
      for (int tdv = 0; tdv < 4; tdv++)
        #pragma unroll
        for (int rg = 0; rg < 4; rg++) o[j][tdv][rg] *= cr[rg];
    }

    // O += P * V : B-operand from V^T tile (row = dv, cols = keys)
    #pragma unroll
    for (int tdv = 0; tdv < 4; tdv++) {
      const u16* vp = lV + (tdv * 16 + r16) * LDK;
      bf16x8 vf0 = ld8(vp + g * 4, vp + 16 + g * 4);
      bf16x8 vf1 = ld8(vp + 32 + g * 4, vp + 48 + g * 4);
      #pragma unroll
      for (int j = 0; j < 2; j++) {
        o[j][tdv] = mma(pa[j][0], vf0, o[j][tdv]);
        o[j][tdv] = mma(pa[j][1], vf1, o[j][tdv]);
      }
    }
  }

  #pragma unroll
  for (int j = 0; j < 2; j++) {
    float li[4];
    #pragma unroll
    for (int rg = 0; rg < 4; rg++) li[rg] = 1.0f / __shfl(lrun[j], g * 4 + rg);
    #pragma unroll
    for (int tdv = 0; tdv < 4; tdv++)
      #pragma unroll
      for (int rg = 0; rg < 4; rg++) {
        int s = q0 + j * 16 + g * 4 + rg;
        ctx[((b * 2048 + s) * 1024) + h * 64 + tdv * 16 + r16] = f2bf(o[j][tdv][rg] * li[rg]);
      }
  }
}

// ---------------- output projection: out = ctx * proj_w^T + proj_b (f32 out) ----------------
__global__ __launch_bounds__(256) void k_gemm_proj(const u16* __restrict__ ctx,
                                                   const u16* __restrict__ pwb,
                                                   const float* __restrict__ pb,
                                                   float* __restrict__ out) {
  __shared__ __align__(16) u16 lA[128 * LDK];
  __shared__ __align__(16) u16 lB[128 * LDK];
  f32x4 acc[4][4] = {};
  const int bm = blockIdx.x * 128, bn = blockIdx.y * 128;
  gemm128(ctx, pwb, lA, lB, bm, bn, acc);
  const int lane = threadIdx.x & 63, wave = threadIdx.x >> 6;
  const int wrow = wave >> 1, wcol = wave & 1;
  const int g = lane >> 4, r16 = lane & 15;
  #pragma unroll
  for (int nj = 0; nj < 4; nj++) {
    int col = bn + wcol * 64 + nj * 16 + r16;
    float bias = pb[col];
    #pragma unroll
    for (int mi = 0; mi < 4; mi++) {
      int mbase = bm + wrow * 64 + mi * 16 + g * 4;
      #pragma unroll
      for (int rg = 0; rg < 4; rg++)
        out[(mbase + rg) * 1024 + col] = acc[mi][nj][rg] + bias;
    }
  }
}

extern "C" void kernel_launch(void* const* d_in, const int* in_sizes, int n_in,
                              void* d_out, int out_size, void* d_ws, size_t ws_size,
                              hipStream_t stream) {
  const float* x      = (const float*)d_in[0];
  const float* qkv_w  = (const float*)d_in[1];
  const float* qkv_b  = (const float*)d_in[2];
  const float* proj_w = (const float*)d_in[3];
  const float* proj_b = (const float*)d_in[4];
  float* out = (float*)d_out;
  char* ws = (char*)d_ws;

  // workspace layout (bytes), total 92,274,688
  u16* xb  = (u16*)(ws);                 // x as bf16            [8192][1024]  16.78MB
  u16* wb  = (u16*)(ws + 16777216);      // qkv_w bf16           [3072][1024]   6.29MB
  u16* pwb = (u16*)(ws + 23068672);      // proj_w bf16          [1024][1024]   2.10MB
  u16* Qs  = (u16*)(ws + 25165824);      // Q*0.125 bf16         [64][2048][64] 16.78MB
  u16* Ks  = (u16*)(ws + 41943040);      // K bf16               [64][2048][64] 16.78MB
  u16* Vt  = (u16*)(ws + 58720256);      // V^T bf16             [64][64][2048] 16.78MB
  u16* ctx = (u16*)(ws + 75497472);      // attn out bf16        [8192][1024]  16.78MB

  cvt_bf16<<<2048, 256, 0, stream>>>(x, xb, 8388608 / 4);
  cvt_bf16<<<1024, 256, 0, stream>>>(qkv_w, wb, 3145728 / 4);
  cvt_bf16<<<512, 256, 0, stream>>>(proj_w, pwb, 1048576 / 4);
  k_gemm_qkv<<<dim3(64, 24), 256, 0, stream>>>(xb, wb, qkv_b, Qs, Ks, Vt);
  k_attn<<<dim3(16, 64), 256, 0, stream>>>(Qs, Ks, Vt, ctx);
  k_gemm_proj<<<dim3(64, 8), 256, 0, stream>>>(ctx, pwb, proj_b, out);
}

// Round 2
// 230.585 us; speedup vs baseline: 1.3100x; 1.3100x over previous
//
#include <hip/hip_runtime.h>
#include <stdint.h>

typedef float f32x4 __attribute__((ext_vector_type(4)));
typedef short bf16x8 __attribute__((ext_vector_type(8)));
typedef unsigned short u16;
typedef unsigned int u32;

#define LDK 72           // GEMM LDS row stride (elems); b128 frag reads at this stride are bank-even
#define VST 136          // attn V^T LDS row stride (elems), 16B-aligned rows
#define SCL2 0.1803368801111243f   // 0.125 * log2(e): softmax scale folded to exp2 domain

static __device__ __forceinline__ u16 f2bf(float f) {
  union { float f; u32 u; } x; x.f = f;
  return (u16)((x.u + 0x7FFFu + ((x.u >> 16) & 1u)) >> 16);  // RNE
}

static __device__ __forceinline__ u32 pk2(float lo, float hi) {
  u32 r;
  asm("v_cvt_pk_bf16_f32 %0, %1, %2" : "=v"(r) : "v"(lo), "v"(hi));
  return r;
}

static __device__ __forceinline__ bf16x8 ld8(const u16* p0, const u16* p1) {
  bf16x8 v;
  uint2* pv = (uint2*)&v;
  pv[0] = *(const uint2*)p0;
  pv[1] = *(const uint2*)p1;
  return v;
}

static __device__ __forceinline__ f32x4 mma(bf16x8 a, bf16x8 b, f32x4 c) {
  return __builtin_amdgcn_mfma_f32_16x16x32_bf16(a, b, c, 0, 0, 0);
}

// ---------------- f32 -> bf16 convert ----------------
__global__ __launch_bounds__(256) void cvt_bf16(const float* __restrict__ in,
                                                u16* __restrict__ out, int n4) {
  int i = blockIdx.x * blockDim.x + threadIdx.x;
  int stride = gridDim.x * blockDim.x;
  for (; i < n4; i += stride) {
    float4 v = ((const float4*)in)[i];
    ushort4 o;
    o.x = f2bf(v.x); o.y = f2bf(v.y); o.z = f2bf(v.z); o.w = f2bf(v.w);
    ((ushort4*)out)[i] = o;
  }
}

// ---------------- shared 128x128x(K=1024) bf16 GEMM core: C = A * B^T ----------------
static __device__ __forceinline__ void gemm128(const u16* __restrict__ A,
                                               const u16* __restrict__ Bmat,
                                               u16* lA, u16* lB,
                                               int bm, int bn, f32x4 (&acc)[4][4]) {
  const int t = threadIdx.x;
  const int lane = t & 63, wave = t >> 6;
  const int wr = wave >> 1, wc = wave & 1;
  const int g = lane >> 4, r16 = lane & 15;
  for (int kt = 0; kt < 1024; kt += 64) {
    __syncthreads();
    #pragma unroll
    for (int i = 0; i < 4; i++) {
      int ci = i * 256 + t;
      int r = ci >> 3, c = (ci & 7) * 8;
      *(uint4*)(lA + r * LDK + c) = *(const uint4*)(A + (bm + r) * 1024 + kt + c);
      *(uint4*)(lB + r * LDK + c) = *(const uint4*)(Bmat + (bn + r) * 1024 + kt + c);
    }
    __syncthreads();
    #pragma unroll
    for (int kk = 0; kk < 2; kk++) {
      bf16x8 af[4], bfr[4];
      #pragma unroll
      for (int mi = 0; mi < 4; mi++)
        af[mi] = *(const bf16x8*)(lA + (wr * 64 + mi * 16 + r16) * LDK + kk * 32 + g * 8);
      #pragma unroll
      for (int nj = 0; nj < 4; nj++)
        bfr[nj] = *(const bf16x8*)(lB + (wc * 64 + nj * 16 + r16) * LDK + kk * 32 + g * 8);
      #pragma unroll
      for (int mi = 0; mi < 4; mi++)
        #pragma unroll
        for (int nj = 0; nj < 4; nj++)
          acc[mi][nj] = mma(af[mi], bfr[nj], acc[mi][nj]);
    }
  }
}

// ---------------- QKV projection + scatter to per-head Q,K,V^T (bf16) ----------------
__global__ __launch_bounds__(256) void k_gemm_qkv(const u16* __restrict__ xb,
                                                  const u16* __restrict__ wb,
                                                  const float* __restrict__ qkv_b,
                                                  u16* __restrict__ Qs,
                                                  u16* __restrict__ Ks,
                                                  u16* __restrict__ Vt) {
  __shared__ __align__(16) u16 lds[2 * 128 * LDK];   // 36 KiB; reused for V transpose
  f32x4 acc[4][4] = {};
  const int bm = blockIdx.x * 128, bn = blockIdx.y * 128;
  gemm128(xb, wb, lds, lds + 128 * LDK, bm, bn, acc);
  const int t = threadIdx.x, lane = t & 63, wave = t >> 6;
  const int wr = wave >> 1, wc = wave & 1;
  const int g = lane >> 4, r16 = lane & 15;
  if (bn < 2048) {
    // Q/K blocks: direct (s-major) coalesced-ish writes
    #pragma unroll
    for (int nj = 0; nj < 4; nj++) {
      int f = bn + wc * 64 + nj * 16 + r16;
      float bias = qkv_b[f];
      int which = f >> 10;                      // 0=q 1=k
      int fl = f & 1023;
      int h = fl >> 6, dd = fl & 63;
      u16* base = which ? Ks : Qs;
      float scl = which ? 1.f : SCL2;
      #pragma unroll
      for (int mi = 0; mi < 4; mi++) {
        int mb = bm + wr * 64 + mi * 16 + g * 4;
        #pragma unroll
        for (int rg = 0; rg < 4; rg++) {
          int m = mb + rg;
          int b = m >> 11, s = m & 2047;
          base[(((b * 16 + h) * 2048) + s) * 64 + dd] = f2bf((acc[mi][nj][rg] + bias) * scl);
        }
      }
    }
  } else {
    // V blocks: transpose via LDS, then coalesced uint4 stores into Vt[dv][s]
    __syncthreads();                            // other waves may still read gemm LDS
    #pragma unroll
    for (int nj = 0; nj < 4; nj++) {
      int fl = wc * 64 + nj * 16 + r16;         // 0..127
      float bias = qkv_b[bn + fl];
      #pragma unroll
      for (int mi = 0; mi < 4; mi++) {
        int ml = wr * 64 + mi * 16 + g * 4;
        *(u32*)(lds + fl * 144 + ml)     = pk2(acc[mi][nj][0] + bias, acc[mi][nj][1] + bias);
        *(u32*)(lds + fl * 144 + ml + 2) = pk2(acc[mi][nj][2] + bias, acc[mi][nj][3] + bias);
      }
    }
    __syncthreads();
    int b = bm >> 11, s0 = bm & 2047;
    #pragma unroll
    for (int i = 0; i < 8; i++) {
      int fl = i * 16 + (t >> 4);
      int m8 = (t & 15) * 8;
      uint4 val = *(uint4*)(lds + fl * 144 + m8);
      int f = bn + fl - 2048;
      int h = f >> 6, dd = f & 63;
      *(uint4*)(Vt + (((b * 16 + h) * 64) + dd) * 2048 + s0 + m8) = val;
    }
  }
}

// ---------------- flash attention: 128 q rows/block, 4 waves x 32 q, KV tile 128 ----------------
__global__ __launch_bounds__(256, 2) void k_attn(const u16* __restrict__ Qs,
                                                 const u16* __restrict__ Ks,
                                                 const u16* __restrict__ Vt,
                                                 u16* __restrict__ ctx) {
  __shared__ __align__(16) u16 lK[128 * 64];    // XOR-swizzled (16B granule), 16 KiB
  __shared__ __align__(16) u16 lV[64 * VST];    // [dv][key] stride 136, 17 KiB
  const int bh = blockIdx.y, qt = blockIdx.x;
  const int b = bh >> 4, h = bh & 15;
  const u16* Qb = Qs + bh * (2048 * 64);
  const u16* Kb = Ks + bh * (2048 * 64);
  const u16* Vb = Vt + bh * (64 * 2048);
  const int t = threadIdx.x, lane = t & 63, wave = t >> 6;
  const int g = lane >> 4, r16 = lane & 15;
  const int q0 = qt * 128 + wave * 32;

  // Q fragments (B-operand of swapped QK^T), contiguous-k mapping: reg i <-> k = kk*32+g*8+i
  bf16x8 qf[2][2];
  #pragma unroll
  for (int j = 0; j < 2; j++)
    #pragma unroll
    for (int kk = 0; kk < 2; kk++)
      qf[j][kk] = *(const bf16x8*)(Qb + (q0 + j * 16 + r16) * 64 + kk * 32 + g * 8);

  float mrun[2] = {-INFINITY, -INFINITY};
  float lrun[2] = {0.f, 0.f};
  f32x4 o[2][4] = {};

  for (int s0 = 0; s0 < 2048; s0 += 128) {
    __syncthreads();
    #pragma unroll
    for (int i = 0; i < 4; i++) {               // stage K tile 128x64 (swizzled)
      int ci = i * 256 + t;
      int r = ci >> 3, c8 = ci & 7;
      int sw = c8 ^ (r & 7);
      *(uint4*)(lK + r * 64 + sw * 8) = *(const uint4*)(Kb + (s0 + r) * 64 + c8 * 8);
    }
    #pragma unroll
    for (int i = 0; i < 4; i++) {               // stage V^T tile 64x128
      int ci = i * 256 + t;
      int r = ci >> 4, c8 = ci & 15;
      *(uint4*)(lV + r * VST + c8 * 8) = *(const uint4*)(Vb + r * 2048 + s0 + c8 * 8);
    }
    __syncthreads();

    // S^T = K * Q^T : lane holds key = ks*16 + 4g + rg, q = r16
    f32x4 st[2][8];
    #pragma unroll
    for (int ks = 0; ks < 8; ks++) {
      int row = ks * 16 + r16;
      const u16* kp = lK + row * 64;
      int sw = row & 7;
      bf16x8 kf0 = *(const bf16x8*)(kp + (g ^ sw) * 8);
      bf16x8 kf1 = *(const bf16x8*)(kp + ((4 + g) ^ sw) * 8);
      #pragma unroll
      for (int j = 0; j < 2; j++) {
        f32x4 z = {0.f, 0.f, 0.f, 0.f};
        z = mma(kf0, qf[j][0], z);
        z = mma(kf1, qf[j][1], z);
        st[j][ks] = z;
      }
    }

    // online softmax in exp2 domain, defer-max
    bf16x8 pa[2][4];
    #pragma unroll
    for (int j = 0; j < 2; j++) {
      float pm = st[j][0][0];
      #pragma unroll
      for (int ks = 0; ks < 8; ks++)
        #pragma unroll
        for (int rg = 0; rg < 4; rg++) pm = fmaxf(pm, st[j][ks][rg]);
      pm = fmaxf(pm, __shfl_xor(pm, 16));
      pm = fmaxf(pm, __shfl_xor(pm, 32));
      if (!__all(pm <= mrun[j] + 10.f)) {       // rescale (rare after tile 0)
        float mn = fmaxf(mrun[j], pm);
        float corr = exp2f(mrun[j] - mn);
        mrun[j] = mn;
        lrun[j] *= corr;
        float cr[4];
        #pragma unroll
        for (int rg = 0; rg < 4; rg++) cr[rg] = __shfl(corr, g * 4 + rg);
        #pragma unroll
        for (int tdv = 0; tdv < 4; tdv++)
          #pragma unroll
          for (int rg = 0; rg < 4; rg++) o[j][tdv][rg] *= cr[rg];
      }
      float m = mrun[j];
      float rs = 0.f;
      #pragma unroll
      for (int ks = 0; ks < 8; ks++) {
        f32x4 ev;
        #pragma unroll
        for (int rg = 0; rg < 4; rg++) {
          ev[rg] = exp2f(st[j][ks][rg] - m);
          rs += ev[rg];
        }
        st[j][ks] = ev;
      }
      rs += __shfl_xor(rs, 16);
      rs += __shfl_xor(rs, 32);
      lrun[j] += rs;
      #pragma unroll
      for (int kb = 0; kb < 4; kb++) {
        u32 w0 = pk2(st[j][kb * 2][0], st[j][kb * 2][1]);
        u32 w1 = pk2(st[j][kb * 2][2], st[j][kb * 2][3]);
        u32 w2 = pk2(st[j][kb * 2 + 1][0], st[j][kb * 2 + 1][1]);
        u32 w3 = pk2(st[j][kb * 2 + 1][2], st[j][kb * 2 + 1][3]);
        u32* pw = (u32*)&pa[j][kb];
        pw[0] = w0; pw[1] = w1; pw[2] = w2; pw[3] = w3;
      }
    }

    // O += P * V
    #pragma unroll
    for (int kb = 0; kb < 4; kb++)
      #pragma unroll
      for (int tdv = 0; tdv < 4; tdv++) {
        const u16* vp = lV + (tdv * 16 + r16) * VST + kb * 32 + g * 4;
        bf16x8 vf = ld8(vp, vp + 16);
        #pragma unroll
        for (int j = 0; j < 2; j++)
          o[j][tdv] = mma(pa[j][kb], vf, o[j][tdv]);
      }
  }

  #pragma unroll
  for (int j = 0; j < 2; j++) {
    float li[4];
    #pragma unroll
    for (int rg = 0; rg < 4; rg++) li[rg] = 1.0f / __shfl(lrun[j], g * 4 + rg);
    #pragma unroll
    for (int tdv = 0; tdv < 4; tdv++)
      #pragma unroll
      for (int rg = 0; rg < 4; rg++) {
        int s = q0 + j * 16 + g * 4 + rg;
        ctx[((b * 2048 + s) * 1024) + h * 64 + tdv * 16 + r16] = f2bf(o[j][tdv][rg] * li[rg]);
      }
  }
}

// ---------------- output projection ----------------
__global__ __launch_bounds__(256) void k_gemm_proj(const u16* __restrict__ ctx,
                                                   const u16* __restrict__ pwb,
                                                   const float* __restrict__ pb,
                                                   float* __restrict__ out) {
  __shared__ __align__(16) u16 lds[2 * 128 * LDK];
  f32x4 acc[4][4] = {};
  const int bm = blockIdx.x * 128, bn = blockIdx.y * 128;
  gemm128(ctx, pwb, lds, lds + 128 * LDK, bm, bn, acc);
  const int lane = threadIdx.x & 63, wave = threadIdx.x >> 6;
  const int wr = wave >> 1, wc = wave & 1;
  const int g = lane >> 4, r16 = lane & 15;
  #pragma unroll
  for (int nj = 0; nj < 4; nj++) {
    int col = bn + wc * 64 + nj * 16 + r16;
    float bias = pb[col];
    #pragma unroll
    for (int mi = 0; mi < 4; mi++) {
      int mb = bm + wr * 64 + mi * 16 + g * 4;
      #pragma unroll
      for (int rg = 0; rg < 4; rg++)
        out[(mb + rg) * 1024 + col] = acc[mi][nj][rg] + bias;
    }
  }
}

extern "C" void kernel_launch(void* const* d_in, const int* in_sizes, int n_in,
                              void* d_out, int out_size, void* d_ws, size_t ws_size,
                              hipStream_t stream) {
  const float* x      = (const float*)d_in[0];
  const float* qkv_w  = (const float*)d_in[1];
  const float* qkv_b  = (const float*)d_in[2];
  const float* proj_w = (const float*)d_in[3];
  const float* proj_b = (const float*)d_in[4];
  float* out = (float*)d_out;
  char* ws = (char*)d_ws;

  u16* xb  = (u16*)(ws);                 // [8192][1024]
  u16* wb  = (u16*)(ws + 16777216);      // [3072][1024]
  u16* pwb = (u16*)(ws + 23068672);      // [1024][1024]
  u16* Qs  = (u16*)(ws + 25165824);      // Q*SCL2      [64][2048][64]
  u16* Ks  = (u16*)(ws + 41943040);      // K           [64][2048][64]
  u16* Vt  = (u16*)(ws + 58720256);      // V^T         [64][64][2048]
  u16* ctx = (u16*)(ws + 75497472);      // attn out    [8192][1024]

  cvt_bf16<<<2048, 256, 0, stream>>>(x, xb, 8388608 / 4);
  cvt_bf16<<<1024, 256, 0, stream>>>(qkv_w, wb, 3145728 / 4);
  cvt_bf16<<<512, 256, 0, stream>>>(proj_w, pwb, 1048576 / 4);
  k_gemm_qkv<<<dim3(64, 24), 256, 0, stream>>>(xb, wb, qkv_b, Qs, Ks, Vt);
  k_attn<<<dim3(16, 64), 256, 0, stream>>>(Qs, Ks, Vt, ctx);
  k_gemm_proj<<<dim3(64, 8), 256, 0, stream>>>(ctx, pwb, proj_b, out);
}